// Round 19
// baseline (399.240 us; speedup 1.0000x reference)
//
#include <hip/hip_runtime.h>
#include <hip/hip_cooperative_groups.h>

namespace cg = cooperative_groups;

#define HD 257
#define WD 257
#define NB (8 * HD)    // 2056 (b,y)-row buckets
#define NCHUNK 32      // chunks per batch
#define CAPC 32        // per-(bucket,chunk) slot capacity (lambda~4 -> safe)
#define BPTS 1024      // bin: points per chunk-task
#define COUT 64
#define LROW 17        // accum LDS row stride (floats): breaks x*16 bank pattern
#define GPTS 64        // gather: points per tile
#define SMEM_BYTES 22016  // max(bin 1028, accum 17604, gather 22016)

typedef unsigned int uint;
typedef unsigned short ushort;
typedef short short8 __attribute__((ext_vector_type(8)));
typedef float f32x4 __attribute__((ext_vector_type(4)));

// f32 -> bf16 RNE
__device__ __forceinline__ uint pack_bf16(float a, float b) {
    uint ua = __float_as_uint(a), ub = __float_as_uint(b);
    ua += 0x7fffu + ((ua >> 16) & 1u);
    ub += 0x7fffu + ((ub >> 16) & 1u);
    return (ua >> 16) | (ub & 0xffff0000u);
}
__device__ __forceinline__ unsigned short bf16_1(float a) {
    uint ua = __float_as_uint(a);
    ua += 0x7fffu + ((ua >> 16) & 1u);
    return (unsigned short)(ua >> 16);
}

// One cooperative kernel: bin -> grid.sync -> accum -> grid.sync -> gather.
// Phase bodies identical to the round-15 best; LDS reused via char union.
__global__ __launch_bounds__(256, 4) void fused_kernel(
    const float* __restrict__ xyzp,
    const float* __restrict__ feat,
    const float* __restrict__ W,
    const float* __restrict__ bias,
    float* __restrict__ out,
    uint* __restrict__ cnt2,     // [NB][NCHUNK]
    ushort* __restrict__ pidx,   // [NB][NCHUNK][CAPC]
    uint* __restrict__ voxn,     // [S][8] normalized bf16 pairs
    int N, int logN, int ntiles) {
    cg::grid_group grid = cg::this_grid();
    __shared__ __align__(16) char smem[SMEM_BYTES];
    const int tid = threadIdx.x;

    // ================= phase 1: bin (256 tasks, grid-stride) =================
    {
        uint* hist = (uint*)smem;
        for (int task = blockIdx.x; task < NCHUNK * 8; task += gridDim.x) {
            int chunk = task & (NCHUNK - 1);
            int b = task >> 5;               // NCHUNK=32
            int p0 = chunk * BPTS;
            __syncthreads();                 // LDS reuse guard
            for (int i = tid; i < HD; i += 256) hist[i] = 0u;
            __syncthreads();

            const float4* xp = reinterpret_cast<const float4*>(xyzp) + (size_t)b * N;
            uint rec[BPTS / 256];
#pragma unroll
            for (int k = 0; k < BPTS / 256; ++k) {
                int i = p0 + tid + k * 256;
                float4 v = xp[i];
                int y = (int)fminf(fmaxf(rintf(v.y * 256.0f), 0.0f), 256.0f);
                uint r = atomicAdd(&hist[y], 1u);   // LDS only
                rec[k] = (uint)y | (r << 9);
            }
            __syncthreads();

            for (int y = tid; y < HD; y += 256)
                cnt2[(size_t)(b * HD + y) * NCHUNK + chunk] = min(hist[y], (uint)CAPC);

#pragma unroll
            for (int k = 0; k < BPTS / 256; ++k) {
                int y = rec[k] & 511;
                uint r = rec[k] >> 9;
                if (r < CAPC)
                    pidx[((size_t)(b * HD + y) * NCHUNK + chunk) * CAPC + r] =
                        (ushort)(p0 + tid + k * 256);
            }
        }
    }
    __threadfence();
    grid.sync();

    // ================= phase 2: accum (2056 buckets, grid-stride) ============
    {
        float* l = (float*)smem;                       // WD*LROW floats
        uint* pc = (uint*)(smem + 4 * WD * LROW);      // NCHUNK counts
        for (int bucket = blockIdx.x; bucket < NB; bucket += gridDim.x) {
            int b = bucket / HD;                       // const-div -> magic mul
            __syncthreads();                           // LDS reuse guard
            for (int i = tid; i < WD * LROW; i += 256) l[i] = 0.0f;
            if (tid < NCHUNK)
                pc[tid] = cnt2[(size_t)bucket * NCHUNK + tid];
            __syncthreads();

#pragma unroll
            for (int s = 0; s < NCHUNK * CAPC; s += 256) {
                int slot = s + tid;
                int c = slot >> 5;                     // chunk: CAPC=32
                int j = slot & (CAPC - 1);
                if ((uint)j < pc[c]) {                 // predicated: ~12.5% density
                    uint lp = pidx[((size_t)bucket * NCHUNK + c) * CAPC + j];
                    int p = (b << logN) + (int)lp;
                    float4 v = reinterpret_cast<const float4*>(xyzp)[p];
                    int x = (int)fminf(fmaxf(rintf(v.x * 256.0f), 0.0f), 256.0f);
                    float* cell = l + x * LROW;
                    atomicAdd(&cell[0], v.w);
                    atomicAdd(&cell[1], 1.0f - v.w);
                    const float2* f2 = reinterpret_cast<const float2*>(feat + (size_t)p * 14);
#pragma unroll
                    for (int jj = 0; jj < 7; ++jj) {
                        float2 fv = f2[jj];
                        atomicAdd(&cell[2 + 2 * jj], fv.x);
                        atomicAdd(&cell[3 + 2 * jj], fv.y);
                    }
                }
            }
            __syncthreads();

            for (int x = tid; x < WD; x += 256) {
                const float* c = l + x * LROW;
                float inv = __builtin_amdgcn_rcpf(fmaxf(c[0] + c[1], 1.0f));
                uint o[8];
#pragma unroll
                for (int j = 0; j < 8; ++j)
                    o[j] = pack_bf16(c[2 * j] * inv, c[2 * j + 1] * inv);
                uint4* op = reinterpret_cast<uint4*>(voxn + ((size_t)bucket * WD + x) * 8);
                op[0] = make_uint4(o[0], o[1], o[2], o[3]);
                op[1] = make_uint4(o[4], o[5], o[6], o[7]);
            }
        }
    }
    __threadfence();
    grid.sync();

    // ================= phase 3: gather (4096 tiles, grid-stride) =============
    {
        char* sA = smem;                               // GPTS*336
        int* sCell = (int*)(smem + GPTS * 336);
        uint* sYX = (uint*)(smem + GPTS * 336 + GPTS * 4);
        const int lane = tid & 63;
        const int w = tid >> 6;
        const int hi = lane >> 4;
        const int lo = lane & 15;

        // hoisted: B fragments + bias (amortized over ~4 tiles/block)
        short8 bfrag[5];
        float bv = bias[w * 16 + lo];
#pragma unroll
        for (int s = 0; s < 5; ++s) {
            int kbase = s * 32 + hi * 8;
            short8 f;
#pragma unroll
            for (int j = 0; j < 8; ++j) {
                int k = kbase + j;
                float wv = (k < 144) ? W[(size_t)k * 64 + w * 16 + lo] : 0.0f;
                f[j] = (short)bf16_1(wv);
            }
            bfrag[s] = f;
        }
        // hoisted: zero-pad k in [144,160) — A-build never touches bytes 288..336
        __syncthreads();                               // LDS reuse guard vs phase 2
        if (tid < GPTS * 2) {
            int i = tid >> 1, h = tid & 1;
            *reinterpret_cast<uint4*>(sA + i * 336 + 288 + h * 16) = make_uint4(0, 0, 0, 0);
        }

        for (int tile = blockIdx.x; tile < ntiles; tile += gridDim.x) {
            int p0 = tile * GPTS;
            __syncthreads();                           // prev MFMA done before rewrite
            if (tid < GPTS) {
                float4 v = reinterpret_cast<const float4*>(xyzp)[p0 + tid];
                int y = (int)fminf(fmaxf(rintf(v.y * 256.0f), 0.0f), 256.0f);
                int x = (int)fminf(fmaxf(rintf(v.x * 256.0f), 0.0f), 256.0f);
                int b = (p0 + tid) >> logN;
                sCell[tid] = (b * HD + y) * WD + x;
                sYX[tid] = ((uint)y << 16) | (uint)x;
            }
            __syncthreads();

            // A build: 18 chunks/point (3 dy-segs x 3 kx x 2 halves of 16 B)
            for (int idx = tid; idx < GPTS * 18; idx += 256) {
                int i = idx / 18;
                int r = idx - i * 18;
                int seg = r / 6;          // dy+1
                int h = r - seg * 6;
                int kx = h >> 1;
                int half = h & 1;
                uint yx = sYX[i];
                int y = (int)(yx >> 16), x = (int)(yx & 0xffffu);
                int ny = y + seg - 1, nx = x + kx - 1;
                uint4 val = make_uint4(0, 0, 0, 0);
                if ((uint)ny <= 256u && (uint)nx <= 256u) {
                    size_t ncell = (size_t)sCell[i] + (size_t)((seg - 1) * WD + (kx - 1));
                    val = *reinterpret_cast<const uint4*>(
                        reinterpret_cast<const char*>(voxn) + ncell * 32 + (size_t)half * 16);
                }
                *reinterpret_cast<uint4*>(sA + i * 336 + (seg * 3 + kx) * 32 + half * 16) = val;
            }
            __syncthreads();

            f32x4 acc[4];
#pragma unroll
            for (int mt = 0; mt < 4; ++mt) acc[mt] = (f32x4){bv, bv, bv, bv};

#pragma unroll
            for (int mt = 0; mt < 4; ++mt) {
                const char* abase = sA + (mt * 16 + lo) * 336 + hi * 16;
#pragma unroll
                for (int s = 0; s < 5; ++s) {
                    short8 a = *reinterpret_cast<const short8*>(abase + s * 64);
                    acc[mt] = __builtin_amdgcn_mfma_f32_16x16x32_bf16(a, bfrag[s], acc[mt], 0, 0, 0);
                }
            }

            // store: D col = lane&15, row = hi*4 + reg (m89-verified)
#pragma unroll
            for (int mt = 0; mt < 4; ++mt)
#pragma unroll
                for (int r = 0; r < 4; ++r) {
                    int row = mt * 16 + hi * 4 + r;
                    out[(size_t)(p0 + row) * 64 + w * 16 + lo] = acc[mt][r];
                }
        }
    }
}

extern "C" void kernel_launch(void* const* d_in, const int* in_sizes, int n_in,
                              void* d_out, int out_size, void* d_ws, size_t ws_size,
                              hipStream_t stream) {
    const float* xyzp = (const float*)d_in[0];
    const float* feat = (const float*)d_in[1];
    const float* W    = (const float*)d_in[2];
    const float* bias = (const float*)d_in[3];
    float* out = (float*)d_out;

    const int BN = in_sizes[0] / 4;  // 262144
    const int B = 8;
    int N = BN / B;                  // 32768
    int logN = 0;
    while ((1 << logN) < N) ++logN;  // 15
    int ntiles = BN / GPTS;          // 4096

    // ws layout: cnt2 | pidx | voxn  ~= 21.4 MB
    uint* cnt2 = (uint*)d_ws;                                        // NB*32*4
    ushort* pidx = (ushort*)((char*)cnt2 + (size_t)NB * NCHUNK * 4); // NB*32*32*2
    uint* voxn = (uint*)((char*)pidx + (size_t)NB * NCHUNK * CAPC * 2);
    (void)ws_size;

    // co-residency-safe grid for cooperative launch (host query; capture-safe)
    int maxBlocksPerCU = 0;
    hipOccupancyMaxActiveBlocksPerMultiprocessor(&maxBlocksPerCU, fused_kernel, 256, 0);
    if (maxBlocksPerCU < 1) maxBlocksPerCU = 1;
    int grid = maxBlocksPerCU * 256;
    if (grid > ntiles) grid = ntiles;

    void* args[] = {(void*)&xyzp, (void*)&feat, (void*)&W, (void*)&bias, (void*)&out,
                    (void*)&cnt2, (void*)&pidx, (void*)&voxn, (void*)&N, (void*)&logN,
                    (void*)&ntiles};
    hipLaunchCooperativeKernel((void*)fused_kernel, dim3(grid), dim3(256), args, 0, stream);
}

// Round 20
// 67.325 us; speedup vs baseline: 5.9300x; 5.9300x over previous
//
#include <hip/hip_runtime.h>

#define HD 257
#define WD 257
#define NB (8 * HD)    // 2056 (b,y)-row buckets
#define NCHUNK 32      // chunks per batch
#define CAPC 32        // per-(bucket,chunk) slot capacity (lambda~4 -> safe)
#define BPTS 1024      // bin: points per block
#define COUT 64
#define LROW 17        // accum LDS row stride (floats): breaks x*16 bank pattern
#define GPTS 64        // gather: points per block

typedef unsigned int uint;
typedef unsigned short ushort;
typedef short short8 __attribute__((ext_vector_type(8)));
typedef float f32x4 __attribute__((ext_vector_type(4)));

// f32 -> bf16 RNE
__device__ __forceinline__ uint pack_bf16(float a, float b) {
    uint ua = __float_as_uint(a), ub = __float_as_uint(b);
    ua += 0x7fffu + ((ua >> 16) & 1u);
    ub += 0x7fffu + ((ub >> 16) & 1u);
    return (ua >> 16) | (ub & 0xffff0000u);
}
__device__ __forceinline__ unsigned short bf16_1(float a) {
    uint ua = __float_as_uint(a);
    ua += 0x7fffu + ((ua >> 16) & 1u);
    return (unsigned short)(ua >> 16);
}

// K1: bin — NO global atomics, no zero pass. Block (chunk,b): LDS histogram
// of its 1024 points, chunk-local ranks, plain stores of cnt2 + pidx.
__global__ __launch_bounds__(256) void bin_kernel(
    const float* __restrict__ xyzp,
    uint* __restrict__ cnt2,     // [NB][NCHUNK]
    ushort* __restrict__ pidx,   // [NB][NCHUNK][CAPC] local point idx in batch
    int N) {
    __shared__ uint hist[HD];
    const int tid = threadIdx.x;
    const int chunk = blockIdx.x;
    const int b = blockIdx.y;
    const int p0 = chunk * BPTS;
    for (int i = tid; i < HD; i += 256) hist[i] = 0u;
    __syncthreads();

    const float4* xp = reinterpret_cast<const float4*>(xyzp) + (size_t)b * N;
    uint rec[BPTS / 256];
#pragma unroll
    for (int k = 0; k < BPTS / 256; ++k) {
        int i = p0 + tid + k * 256;
        float4 v = xp[i];
        int y = (int)fminf(fmaxf(rintf(v.y * 256.0f), 0.0f), 256.0f);
        uint r = atomicAdd(&hist[y], 1u);   // LDS only
        rec[k] = (uint)y | (r << 9);
    }
    __syncthreads();

    for (int y = tid; y < HD; y += 256)
        cnt2[(size_t)(b * HD + y) * NCHUNK + chunk] = min(hist[y], (uint)CAPC);

#pragma unroll
    for (int k = 0; k < BPTS / 256; ++k) {
        int y = rec[k] & 511;
        uint r = rec[k] >> 9;
        if (r < CAPC)
            pidx[((size_t)(b * HD + y) * NCHUNK + chunk) * CAPC + r] =
                (ushort)(p0 + tid + k * 256);
    }
}

// K2: accum — one row bucket per block (2056 blocks, 17.5 KB LDS -> 8
// blocks/CU). Predicated slot-grid loop; f32 LDS accumulate; normalize
// (count = ch0+ch1); emit bf16 voxel rows (cached — gather re-reads them).
__global__ __launch_bounds__(256) void accum_kernel(
    const uint* __restrict__ cnt2,
    const ushort* __restrict__ pidx,
    const float* __restrict__ xyzp,
    const float* __restrict__ feat,
    uint* __restrict__ voxn,       // [S][8] normalized bf16 pairs
    int logN) {
    __shared__ float l[WD * LROW];   // 17476 B -> 8 blocks/CU
    __shared__ uint pc[NCHUNK];
    const int tid = threadIdx.x;
    const int bucket = blockIdx.x;
    const int b = bucket / HD;       // const-div -> magic mul
    for (int i = tid; i < WD * LROW; i += 256) l[i] = 0.0f;
    if (tid < NCHUNK)
        pc[tid] = cnt2[(size_t)bucket * NCHUNK + tid];
    __syncthreads();

#pragma unroll
    for (int s = 0; s < NCHUNK * CAPC; s += 256) {
        int slot = s + tid;
        int c = slot >> 5;              // chunk: CAPC=32
        int j = slot & (CAPC - 1);
        if ((uint)j < pc[c]) {          // predicated: ~12.5% density
            uint lp = pidx[((size_t)bucket * NCHUNK + c) * CAPC + j];
            int p = (b << logN) + (int)lp;
            float4 v = reinterpret_cast<const float4*>(xyzp)[p];
            int x = (int)fminf(fmaxf(rintf(v.x * 256.0f), 0.0f), 256.0f);
            float* cell = l + x * LROW;
            atomicAdd(&cell[0], v.w);
            atomicAdd(&cell[1], 1.0f - v.w);
            const float2* f2 = reinterpret_cast<const float2*>(feat + (size_t)p * 14);
#pragma unroll
            for (int jj = 0; jj < 7; ++jj) {
                float2 fv = f2[jj];
                atomicAdd(&cell[2 + 2 * jj], fv.x);
                atomicAdd(&cell[3 + 2 * jj], fv.y);
            }
        }
    }
    __syncthreads();

    for (int x = tid; x < WD; x += 256) {
        const float* c = l + x * LROW;
        float inv = __builtin_amdgcn_rcpf(fmaxf(c[0] + c[1], 1.0f));
        uint o[8];
#pragma unroll
        for (int j = 0; j < 8; ++j)
            o[j] = pack_bf16(c[2 * j] * inv, c[2 * j + 1] * inv);
        uint4* op = reinterpret_cast<uint4*>(voxn + ((size_t)bucket * WD + x) * 8);
        op[0] = make_uint4(o[0], o[1], o[2], o[3]);
        op[1] = make_uint4(o[4], o[5], o[6], o[7]);
    }
}

// K3: 64 points / 256 thr (4 waves). A[64][K=160] bf16 in LDS (336 B row).
// Wave w computes cols w*16..w*16+15 over all 64 rows. k = (dy*3+dx)*16 + c.
// Out stores are NON-TEMPORAL: write-once data must not evict voxn from L2/L3.
__global__ __launch_bounds__(256) void gather_mfma_kernel(
    const float* __restrict__ xyzp,
    const uint* __restrict__ voxn,   // [S][8] normalized bf16 pairs
    const float* __restrict__ W,     // [9][16][64] f32 = [144][64]
    const float* __restrict__ bias,
    float* __restrict__ out, int logN) {
    __shared__ __align__(16) char sA[GPTS * 336];  // 21504 B
    __shared__ int sCell[GPTS];
    __shared__ uint sYX[GPTS];

    const int tid = threadIdx.x;
    const int lane = tid & 63;
    const int w = tid >> 6;
    const int p0 = blockIdx.x * GPTS;
    const int hi = lane >> 4;
    const int lo = lane & 15;

    // per-point data computed ONCE (threads 0..63)
    if (tid < GPTS) {
        float4 v = reinterpret_cast<const float4*>(xyzp)[p0 + tid];
        int y = (int)fminf(fmaxf(rintf(v.y * 256.0f), 0.0f), 256.0f);
        int x = (int)fminf(fmaxf(rintf(v.x * 256.0f), 0.0f), 256.0f);
        int b = (p0 + tid) >> logN;
        sCell[tid] = (b * HD + y) * WD + x;
        sYX[tid] = ((uint)y << 16) | (uint)x;
    }

    // B fragments (issued before barrier; latency overlaps)
    short8 bfrag[5];
    float bv = bias[w * 16 + lo];
#pragma unroll
    for (int s = 0; s < 5; ++s) {
        int kbase = s * 32 + hi * 8;
        short8 f;
#pragma unroll
        for (int j = 0; j < 8; ++j) {
            int k = kbase + j;
            float wv = (k < 144) ? W[(size_t)k * 64 + w * 16 + lo] : 0.0f;
            f[j] = (short)bf16_1(wv);
        }
        bfrag[s] = f;
    }
    __syncthreads();

    // A build: 18 chunks/point (3 dy-segs x 3 kx x 2 halves of 16 B)
    for (int idx = tid; idx < GPTS * 18; idx += 256) {
        int i = idx / 18;
        int r = idx - i * 18;
        int seg = r / 6;          // dy+1
        int h = r - seg * 6;
        int kx = h >> 1;
        int half = h & 1;
        uint yx = sYX[i];
        int y = (int)(yx >> 16), x = (int)(yx & 0xffffu);
        int ny = y + seg - 1, nx = x + kx - 1;
        uint4 val = make_uint4(0, 0, 0, 0);
        if ((uint)ny <= 256u && (uint)nx <= 256u) {
            size_t ncell = (size_t)sCell[i] + (size_t)((seg - 1) * WD + (kx - 1));
            val = *reinterpret_cast<const uint4*>(
                reinterpret_cast<const char*>(voxn) + ncell * 32 + (size_t)half * 16);
        }
        *reinterpret_cast<uint4*>(sA + i * 336 + (seg * 3 + kx) * 32 + half * 16) = val;
    }
    // zero-pad k in [144,160)
    if (tid < GPTS * 2) {
        int i = tid >> 1, h = tid & 1;
        *reinterpret_cast<uint4*>(sA + i * 336 + 288 + h * 16) = make_uint4(0, 0, 0, 0);
    }
    __syncthreads();

    f32x4 acc[4];
#pragma unroll
    for (int mt = 0; mt < 4; ++mt) acc[mt] = (f32x4){bv, bv, bv, bv};

#pragma unroll
    for (int mt = 0; mt < 4; ++mt) {
        const char* abase = sA + (mt * 16 + lo) * 336 + hi * 16;
#pragma unroll
        for (int s = 0; s < 5; ++s) {
            short8 a = *reinterpret_cast<const short8*>(abase + s * 64);
            acc[mt] = __builtin_amdgcn_mfma_f32_16x16x32_bf16(a, bfrag[s], acc[mt], 0, 0, 0);
        }
    }

    // store: D col = lane&15, row = hi*4 + reg (m89-verified); non-temporal
#pragma unroll
    for (int mt = 0; mt < 4; ++mt)
#pragma unroll
        for (int r = 0; r < 4; ++r) {
            int row = mt * 16 + hi * 4 + r;
            __builtin_nontemporal_store(acc[mt][r],
                                        &out[(size_t)(p0 + row) * 64 + w * 16 + lo]);
        }
}

extern "C" void kernel_launch(void* const* d_in, const int* in_sizes, int n_in,
                              void* d_out, int out_size, void* d_ws, size_t ws_size,
                              hipStream_t stream) {
    const float* xyzp = (const float*)d_in[0];
    const float* feat = (const float*)d_in[1];
    const float* W    = (const float*)d_in[2];
    const float* bias = (const float*)d_in[3];
    float* out = (float*)d_out;

    const int BN = in_sizes[0] / 4;  // 262144
    const int B = 8;
    const int N = BN / B;            // 32768
    int logN = 0;
    while ((1 << logN) < N) ++logN;  // 15

    // ws layout: cnt2 | pidx | voxn  ~= 21.4 MB
    uint* cnt2 = (uint*)d_ws;                                        // NB*32*4 = 263168 B
    ushort* pidx = (ushort*)((char*)cnt2 + (size_t)NB * NCHUNK * 4); // NB*32*32*2 = 4.21 MB
    uint* voxn = (uint*)((char*)pidx + (size_t)NB * NCHUNK * CAPC * 2);  // 16.9 MB
    (void)ws_size;

    dim3 bgrid(NCHUNK, B);           // 32 x 8
    bin_kernel<<<bgrid, 256, 0, stream>>>(xyzp, cnt2, pidx, N);
    accum_kernel<<<NB, 256, 0, stream>>>(cnt2, pidx, xyzp, feat, voxn, logN);
    gather_mfma_kernel<<<BN / GPTS, 256, 0, stream>>>(xyzp, voxn, W, bias, out, logN);
}